// Round 10
// baseline (2570.830 us; speedup 1.0000x reference)
//
#include <hip/hip_runtime.h>
#include <hip/hip_bf16.h>

#define TOT85 1722695ULL  // 85 * 20267

using short8 = __attribute__((ext_vector_type(8))) short;
using f32x4  = __attribute__((ext_vector_type(4))) float;

struct Feat5 { const float* p[5]; };

__device__ __forceinline__ float bfbits2f(short u) {
  return __uint_as_float(((unsigned int)(unsigned short)u) << 16);
}
__device__ __forceinline__ short f2bfbits(float f) {
  __hip_bfloat16 h = __float2bfloat16(f);
  return *reinterpret_cast<short*>(&h);
}
__device__ __forceinline__ void gload_lds16(const void* g, void* l) {
  __builtin_amdgcn_global_load_lds(
      (const __attribute__((address_space(1))) unsigned int*)g,
      (__attribute__((address_space(3))) unsigned int*)l, 16, 0, 0);
}

// level tables: 16-col tiling (heads, 182 tiles) and 32-col tiling (towers, 97 tiles)
#define LVL_TABLES                                                              \
  constexpr int kH[5] = {100, 50, 25, 13, 7};                                   \
  constexpr int kW[5] = {152, 76, 38, 19, 10};                                  \
  constexpr int kNTx[5] = {10, 5, 3, 2, 1};                                     \
  constexpr int kCumT[5] = {0, 130, 165, 177, 181};                             \
  constexpr int kCumHW[5] = {0, 15200, 19000, 19950, 20197};                    \
  constexpr float kInv[5] = {1.f / 121600.f, 1.f / 30400.f, 1.f / 7600.f,       \
                             1.f / 1976.f, 1.f / 560.f};
#define LVL_TABLES32                                                            \
  constexpr int kH[5] = {100, 50, 25, 13, 7};                                   \
  constexpr int kW[5] = {152, 76, 38, 19, 10};                                  \
  constexpr int kNTx32[5] = {5, 3, 2, 1, 1};                                    \
  constexpr int kCumT32[5] = {0, 65, 86, 94, 96};                               \
  constexpr int kCumHW[5] = {0, 15200, 19000, 19950, 20197};                    \
  constexpr float kInv[5] = {1.f / 121600.f, 1.f / 30400.f, 1.f / 7600.f,       \
                             1.f / 1976.f, 1.f / 560.f};

// head-layout repack: [O][256][3][3] f32 -> [tap*8+chunk][NOCP oc][32 ic] bf16
__global__ __launch_bounds__(256) void repack_k(const float* __restrict__ src,
                                                __hip_bfloat16* __restrict__ dst,
                                                int O, int NOCP, int ocoff) {
  int idx = blockIdx.x * 256 + threadIdx.x;
  if (idx >= O * 2304) return;
  int o = idx / 2304;
  int r = idx - o * 2304;
  int i = r / 9;       // ic 0..255
  int t = r - i * 9;   // tap 0..8
  dst[((size_t)(t * 8 + (i >> 5)) * NOCP + (o + ocoff)) * 32 + (i & 31)] =
      __float2bfloat16(src[idx]);
}

// tower-layout repack: [256][256][3][3] f32 -> [ochalf 2][chunk 8][tap 9][128 oc][40] bf16
// (pad shorts 32..39 never read as weights; chunk panel is glds-linear, 92160 B)
__global__ __launch_bounds__(256) void repack_big_k(const float* __restrict__ src,
                                                    __hip_bfloat16* __restrict__ dst) {
  int idx = blockIdx.x * 256 + threadIdx.x;
  if (idx >= 256 * 2304) return;
  int o = idx / 2304;
  int r = idx - o * 2304;
  int i = r / 9;
  int t = r - i * 9;
  dst[((((size_t)(o >> 7) * 8 + (i >> 5)) * 9 + t) * 128 + (o & 127)) * 40 + (i & 31)] =
      __float2bfloat16(src[idx]);
}

__global__ void locations_all_k(float* __restrict__ out) {
  LVL_TABLES
  constexpr int kStride[5] = {8, 16, 32, 64, 128};
  int i = blockIdx.x * 256 + threadIdx.x;
  if (i >= 20267) return;
  int lvl = (i >= 15200) + (i >= 19000) + (i >= 19950) + (i >= 20197);
  int local = i - kCumHW[lvl];
  int W = kW[lvl];
  float s = (float)kStride[lvl];
  int y = local / W, x = local - y * W;
  out[2 * i + 0] = x * s + 0.5f * s;
  out[2 * i + 1] = y * s + 0.5f * s;
}

// ---------------- tower kernel: LDS-weight panel, 512 thr, 8 waves ----------------
// Tile: 256 px (8 rows x 32 cols) x 128 oc (blockIdx.y = oc half). 8 waves =
// wq(col half) x wm(row half) x wn(64-oc half); per wave 64 px x 64 oc, acc[4][4]
// (64 AGPR -> no spill; total regs ~200 < 256). Per chunk (32 ic): the full
// 9-tap x 128-oc weight panel (92 KB, pad-40 rows = 2-way-bank-free) streams
// global->LDS via global_load_lds (zero VGPR, L2-resident source, read ONCE per
// block instead of per-wave-per-K-step -> kills the 41%-of-wall L2 weight stream
// of the register-path engine). K-loop reads both operands from LDS; 2 barriers
// per chunk; input staging is 2-phase (loads issued before barrier 1).
// LDS 121.5 KB -> 1 block/CU, 8 waves (2/SIMD).
template <bool NORM_IN, bool SRC_NCHW>
__global__ __launch_bounds__(512, 2) void conv_tower_k(
    Feat5 feats, const __hip_bfloat16* __restrict__ srcb_base,
    const __hip_bfloat16* __restrict__ wpk, const float* __restrict__ bias,
    const float* __restrict__ statsInBase, const float* __restrict__ gamma,
    const float* __restrict__ beta, __hip_bfloat16* __restrict__ dstBase,
    float* __restrict__ statsOutBase) {
  LVL_TABLES32
  __shared__ __align__(16) short s_in[340 * 40];     // 10 rows x 34 cols halo tile
  __shared__ __align__(16) short s_w[9 * 128 * 40];  // 92,160 B weight panel
  __shared__ float s_red[32];
  __shared__ float s_a[256], s_c[256];

  const int tid = threadIdx.x;
  const int lane = tid & 63;
  const int wave = tid >> 6;       // 0..7
  const int wn = wave & 1;         // 64-oc half within the 128 panel
  const int wm = (wave >> 1) & 1;  // row half
  const int wq = wave >> 2;        // col half
  const int bx = blockIdx.x;
  const int lvl = (bx >= 65) + (bx >= 86) + (bx >= 94) + (bx >= 96);
  const int H = kH[lvl], W = kW[lvl], nTx = kNTx32[lvl];
  const int tloc = bx - kCumT32[lvl];
  const int ty = tloc / nTx, tx = tloc - ty * nTx;
  const int x0 = tx * 32, y0 = ty * 8;
  const int b = blockIdx.z;
  const int ochalf = blockIdx.y;
  const int HW = H * W;
  const size_t lbase = (size_t)2048 * kCumHW[lvl];  // 8*256*cumHW elements
  const int l15 = lane & 15;
  const int kg = lane >> 4;  // 0..3
  const int q8 = (tid & 3) * 8;

  if (tid < 32) s_red[tid] = 0.f;
  if (NORM_IN && tid < 256) {
    const float* statsIn = statsInBase + (size_t)lvl * 4096;
    float inv_cnt = kInv[lvl];
    int g = tid >> 3;
    float s = statsIn[(b * 32 + g) * 2 + 0];
    float ss = statsIn[(b * 32 + g) * 2 + 1];
    float m = s * inv_cnt;
    float var = fmaf(-m, m, ss * inv_cnt);
    float rs = rsqrtf(var + 1e-5f);
    float avv = rs * gamma[tid];
    s_a[tid] = avv;
    s_c[tid] = fmaf(-m, avv, beta[tid]);
  }

  f32x4 acc[4][4];
#pragma unroll
  for (int m = 0; m < 4; ++m)
#pragma unroll
    for (int n = 0; n < 4; ++n) acc[m][n] = (f32x4){0.f, 0.f, 0.f, 0.f};

  const short* wpanel = (const short*)wpk + (size_t)ochalf * (8 * 9 * 128 * 40);

  for (int chunk = 0; chunk < 8; ++chunk) {
    const int ic0 = chunk * 32;

    // ---- phase A: issue input loads into regs (before barrier; overlaps tap tail) ----
    short8 pv[3];
    if (!SRC_NCHW) {
      const short* srcb = (const short*)srcb_base + lbase;
#pragma unroll
      for (int r = 0; r < 3; ++r) {
        int idx = r * 512 + tid;
        pv[r] = (short8)0;
        if (idx < 1360) {  // 340 px x 4 quads
          int px = idx >> 2;
          int prow = px / 34, pcol = px - prow * 34;
          int gy = y0 + prow - 1, gx = x0 + pcol - 1;
          if (gy >= 0 && gy < H && gx >= 0 && gx < W)
            pv[r] = *(const short8*)(srcb +
                                     ((((size_t)b * H + gy) * W + gx) * 256 + ic0 + q8));
        }
      }
    }

    __syncthreads();  // barrier 1: prev chunk's s_in/s_w readers done

    // ---- weight panel glds: 5760 x 16B, wave-uniform dest + lane offset ----
    {
      const short* wsrc = wpanel + (size_t)chunk * (9 * 128 * 40);
#pragma unroll
      for (int r = 0; r < 12; ++r) {
        int u = r * 512 + tid;
        if (u < 5760)  // 5760 = 90 waves * 64: wave-aligned guard
          gload_lds16(wsrc + (size_t)u * 8, s_w + (size_t)(r * 512 + wave * 64) * 8);
      }
    }

    // ---- phase B: input convert + LDS write (covers glds latency) ----
    if (SRC_NCHW) {
      const float* srcf = feats.p[lvl];
      if (tid < 340) {
        int prow = tid / 34, pcol = tid - prow * 34;
        int gy = y0 + prow - 1, gx = x0 + pcol - 1;
        short8 sv[4];
        bool valid = (gy >= 0 && gy < H && gx >= 0 && gx < W);
        if (valid) {
          const float* p = srcf + (((size_t)(b * 256 + ic0)) * H + gy) * W + gx;
#pragma unroll
          for (int q = 0; q < 4; ++q)
#pragma unroll
            for (int j = 0; j < 8; ++j)
              sv[q][j] = f2bfbits(p[(size_t)(q * 8 + j) * HW]);
        } else {
#pragma unroll
          for (int q = 0; q < 4; ++q) sv[q] = (short8)0;
        }
#pragma unroll
        for (int q = 0; q < 4; ++q) *(short8*)(s_in + tid * 40 + q * 8) = sv[q];
      }
    } else {
      float av[8], cv[8];
#pragma unroll
      for (int j = 0; j < 8; ++j) {
        int c2 = ic0 + q8 + j;
        av[j] = s_a[c2];
        cv[j] = s_c[c2];
      }
#pragma unroll
      for (int r = 0; r < 3; ++r) {
        int idx = r * 512 + tid;
        if (idx < 1360) {
          int px = idx >> 2;
          int prow = px / 34, pcol = px - prow * 34;
          int gy = y0 + prow - 1, gx = x0 + pcol - 1;
          short8 o8 = (short8)0;
          if (gy >= 0 && gy < H && gx >= 0 && gx < W) {
#pragma unroll
            for (int j = 0; j < 8; ++j)
              o8[j] = f2bfbits(fmaxf(fmaf(bfbits2f(pv[r][j]), av[j], cv[j]), 0.f));
          }
          *(short8*)(s_in + px * 40 + q8) = o8;
        }
      }
    }
    __syncthreads();  // barrier 2: drains glds (vmcnt 0) + ds_writes

    // ---- 9 taps, barrier-free; both operands from LDS ----
#pragma unroll
    for (int tap = 0; tap < 9; ++tap) {
      const int dy = tap / 3, dx = tap - dy * 3;
      short8 wf[4];
#pragma unroll
      for (int n = 0; n < 4; ++n)
        wf[n] = *(const short8*)(s_w + ((tap * 128 + wn * 64 + n * 16 + l15) * 40 + kg * 8));
      short8 af[4];
#pragma unroll
      for (int m = 0; m < 4; ++m)
        af[m] = *(const short8*)(s_in +
                                 (((wm * 4 + m + dy) * 34 + (wq * 16 + l15 + dx)) * 40 + kg * 8));
#pragma unroll
      for (int m = 0; m < 4; ++m)
#pragma unroll
        for (int n = 0; n < 4; ++n)
          acc[m][n] = __builtin_amdgcn_mfma_f32_16x16x32_bf16(af[m], wf[n], acc[m][n], 0, 0, 0);
    }
  }

  // ---- epilogue: bias, NHWC bf16 store, GN stats ----
  short* dst = (short*)dstBase + lbase;
  const int masks[5] = {1, 2, 4, 16, 32};
#pragma unroll
  for (int n = 0; n < 4; ++n) {
    int oc_g = ochalf * 128 + wn * 64 + n * 16 + l15;
    float bv = bias[oc_g];
    float lsum = 0.f, lssq = 0.f;
#pragma unroll
    for (int m = 0; m < 4; ++m) {
      int oy = y0 + wm * 4 + m;
#pragma unroll
      for (int r = 0; r < 4; ++r) {
        int ox = x0 + wq * 16 + kg * 4 + r;
        bool valid = (oy < H) && (ox < W);
        float v = acc[m][n][r] + bv;
        if (valid) {
          dst[(((size_t)b * H + oy) * W + ox) * 256 + oc_g] = f2bfbits(v);
          lsum += v;
          lssq += v * v;
        }
      }
    }
#pragma unroll
    for (int s = 0; s < 5; ++s) {
      lsum += __shfl_xor(lsum, masks[s], 64);
      lssq += __shfl_xor(lssq, masks[s], 64);
    }
    if ((lane & 55) == 0) {  // lanes 0 and 8: two 8-oc GN sub-groups
      int g2 = (wn * 8 + n * 2 + ((lane >> 3) & 1)) * 2;
      atomicAdd(&s_red[g2 + 0], lsum);
      atomicAdd(&s_red[g2 + 1], lssq);
    }
  }
  __syncthreads();
  float* statsOut = statsOutBase + (size_t)lvl * 4096;
  if (tid < 32) atomicAdd(&statsOut[(size_t)b * 64 + ochalf * 32 + tid], s_red[tid]);
}

// ---------------- head kernel (r9-proven 2Mx2N register path, level-batched) --------
// OUT_MODE: 1 = d_out fp32 (logits oc<80, ctr oc==80 -> ch84);
//           2 = d_out fp32 expf(scale*v) at ch 80+oc.
template <int NREP, int OUT_MODE>
__global__ __launch_bounds__(256, 3) void conv_head_k(
    const __hip_bfloat16* __restrict__ srcb_base, const __hip_bfloat16* __restrict__ wpk,
    const float* __restrict__ bias, const float* __restrict__ bias2,
    const float* __restrict__ statsInBase, const float* __restrict__ gamma,
    const float* __restrict__ beta, float* __restrict__ out,
    const float* __restrict__ scales, int NOCP) {
  LVL_TABLES
  __shared__ __align__(16) short s_in[180 * 40];
  __shared__ float s_a[256], s_c[256];

  const int tid = threadIdx.x;
  const int lane = tid & 63;
  const int wave = tid >> 6;
  const int wm = wave >> 1;
  const int wn = wave & 1;
  const int bx = blockIdx.x;
  const int lvl = (bx >= 130) + (bx >= 165) + (bx >= 177) + (bx >= 181);
  const int H = kH[lvl], W = kW[lvl], nTx = kNTx[lvl];
  const int tloc = bx - kCumT[lvl];
  const int ty = tloc / nTx, tx = tloc - ty * nTx;
  const int x0 = tx * 16, y0 = ty * 8;
  const int b = blockIdx.z;
  const int HW = H * W;
  const size_t lbase = (size_t)2048 * kCumHW[lvl];
  float* out_lvl = out + (size_t)85 * kCumHW[lvl];
  const int l15 = lane & 15;
  const int kg = lane >> 4;
  const int q8 = (tid & 3) * 8;

  {
    const float* statsIn = statsInBase + (size_t)lvl * 4096;
    float inv_cnt = kInv[lvl];
    int g = tid >> 3;
    float s = statsIn[(b * 32 + g) * 2 + 0];
    float ss = statsIn[(b * 32 + g) * 2 + 1];
    float m = s * inv_cnt;
    float var = fmaf(-m, m, ss * inv_cnt);
    float rs = rsqrtf(var + 1e-5f);
    float avv = rs * gamma[tid];
    s_a[tid] = avv;
    s_c[tid] = fmaf(-m, avv, beta[tid]);
  }

  f32x4 acc[4][NREP];
#pragma unroll
  for (int m = 0; m < 4; ++m)
#pragma unroll
    for (int n = 0; n < NREP; ++n) acc[m][n] = (f32x4){0.f, 0.f, 0.f, 0.f};

  const short* wlane = (const short*)wpk + ((wn * NREP * 16 + l15) * 32 + kg * 8);
  const size_t TAPSTR = (size_t)8 * NOCP * 32;

  for (int chunk = 0; chunk < 8; ++chunk) {
    const int ic0 = chunk * 32;
    __syncthreads();
    {
      const short* srcb = (const short*)srcb_base + lbase;
      float av[8], cv[8];
#pragma unroll
      for (int j = 0; j < 8; ++j) {
        int c2 = ic0 + q8 + j;
        av[j] = s_a[c2];
        cv[j] = s_c[c2];
      }
      for (int idx = tid; idx < 720; idx += 256) {
        int pix = idx >> 2;
        int prow = pix / 18;
        int pcol = pix - prow * 18;
        int gy = y0 + prow - 1, gx = x0 + pcol - 1;
        short8 o8 = (short8)0;
        if (gy >= 0 && gy < H && gx >= 0 && gx < W) {
          const short* sp = srcb + ((((size_t)b * H + gy) * W + gx) * 256 + ic0 + q8);
          short8 v8 = *(const short8*)sp;
#pragma unroll
          for (int j = 0; j < 8; ++j)
            o8[j] = f2bfbits(fmaxf(fmaf(bfbits2f(v8[j]), av[j], cv[j]), 0.f));
        }
        *(short8*)(s_in + pix * 40 + q8) = o8;
      }
    }
    __syncthreads();

    const short* wch = wlane + (size_t)chunk * NOCP * 32;
    short8 bwA[NREP], bwB[NREP];
#pragma unroll
    for (int n = 0; n < NREP; ++n) bwA[n] = *(const short8*)(wch + n * 512);

    auto tapbody = [&](int tap, short8* curw, short8* nxtw) {
      if (tap < 8) {
        const short* wt = wch + (size_t)(tap + 1) * TAPSTR;
#pragma unroll
        for (int n = 0; n < NREP; ++n) nxtw[n] = *(const short8*)(wt + n * 512);
      }
      const int dy = tap / 3, dx = tap - dy * 3;
      short8 af[4];
#pragma unroll
      for (int m = 0; m < 4; ++m)
        af[m] = *(const short8*)(s_in + ((wm * 4 + m + dy) * 18 + (l15 + dx)) * 40 + kg * 8);
#pragma unroll
      for (int m = 0; m < 4; ++m)
#pragma unroll
        for (int n = 0; n < NREP; ++n)
          acc[m][n] = __builtin_amdgcn_mfma_f32_16x16x32_bf16(af[m], curw[n], acc[m][n], 0, 0, 0);
    };
#pragma unroll
    for (int tap = 0; tap < 9; tap += 2) {
      tapbody(tap, bwA, bwB);
      if (tap + 1 < 9) tapbody(tap + 1, bwB, bwA);
    }
  }

#pragma unroll
  for (int n = 0; n < NREP; ++n) {
    int oc_l = wn * NREP * 16 + n * 16 + l15;
    int oc_valid = (OUT_MODE == 1) ? 81 : 4;
    float bv;
    if (OUT_MODE == 1)
      bv = (oc_l < 80) ? bias[oc_l] : ((oc_l == 80) ? bias2[0] : 0.f);
    else
      bv = (oc_l < oc_valid) ? bias[oc_l] : 0.f;
#pragma unroll
    for (int m = 0; m < 4; ++m) {
      int oy = y0 + wm * 4 + m;
#pragma unroll
      for (int r = 0; r < 4; ++r) {
        int ox = x0 + kg * 4 + r;
        bool valid = (oy < H) && (ox < W) && (oc_l < oc_valid);
        float v = acc[m][n][r] + bv;
        if (valid) {
          if (OUT_MODE == 1) {
            int och = (oc_l == 80) ? 84 : oc_l;
            out_lvl[(size_t)b * TOT85 + (size_t)och * HW + oy * W + ox] = v;
          } else {
            out_lvl[(size_t)b * TOT85 + (size_t)(80 + oc_l) * HW + oy * W + ox] =
                expf(scales[lvl] * v);
          }
        }
      }
    }
  }
}

extern "C" void kernel_launch(void* const* d_in, const int* in_sizes, int n_in,
                              void* d_out_v, int out_size, void* d_ws, size_t ws_size,
                              hipStream_t stream) {
  (void)in_sizes; (void)n_in; (void)out_size; (void)ws_size;

  Feat5 feats;
  for (int i = 0; i < 5; ++i) feats.p[i] = (const float*)d_in[i];
  Feat5 featsNull;
  for (int i = 0; i < 5; ++i) featsNull.p[i] = nullptr;
  const float* cls_w = (const float*)d_in[5];
  const float* cls_b = (const float*)d_in[6];
  const float* cls_g = (const float*)d_in[7];
  const float* cls_bb = (const float*)d_in[8];
  const float* box_w = (const float*)d_in[9];
  const float* box_b = (const float*)d_in[10];
  const float* box_g = (const float*)d_in[11];
  const float* box_bb = (const float*)d_in[12];
  const float* logits_w = (const float*)d_in[13];
  const float* logits_b = (const float*)d_in[14];
  const float* ctr_w = (const float*)d_in[15];
  const float* ctr_b = (const float*)d_in[16];
  const float* reg_w = (const float*)d_in[17];
  const float* reg_b = (const float*)d_in[18];
  const float* scales = (const float*)d_in[19];
  float* d_out = (float*)d_out_v;

  char* wsp = (char*)d_ws;
  size_t off = 0;
  auto carve = [&](size_t bytes) -> char* {
    char* p = wsp + off;
    off += (bytes + 255) & ~(size_t)255;
    return p;
  };
  const size_t ALLE = (size_t)8 * 20267 * 256;  // all levels concat, NHWC elems
  __hip_bfloat16* bufA = (__hip_bfloat16*)carve(ALLE * 2);
  __hip_bfloat16* bufB = (__hip_bfloat16*)carve(ALLE * 2);
  const size_t TWB = (size_t)2 * 8 * 9 * 128 * 40;  // tower big layout, per conv
  __hip_bfloat16* big_cls = (__hip_bfloat16*)carve(4 * TWB * 2);
  __hip_bfloat16* big_box = (__hip_bfloat16*)carve(4 * TWB * 2);
  __hip_bfloat16* wpk_clsh = (__hip_bfloat16*)carve((size_t)9 * 8 * 96 * 32 * 2);
  __hip_bfloat16* wpk_regh = (__hip_bfloat16*)carve((size_t)9 * 8 * 32 * 32 * 2);
  float* stats_all = (float*)carve((size_t)40 * 512 * 4);

  hipMemsetAsync(stats_all, 0, (size_t)40 * 512 * 4, stream);

  auto rp = [&](const float* s, __hip_bfloat16* d, int O, int NOCP, int ocoff) {
    int total = O * 2304;
    hipLaunchKernelGGL(repack_k, dim3((total + 255) / 256), dim3(256), 0, stream, s, d, O, NOCP,
                       ocoff);
  };
  for (int i = 0; i < 4; ++i) {
    hipLaunchKernelGGL(repack_big_k, dim3(2304), dim3(256), 0, stream,
                       cls_w + (size_t)i * 256 * 2304, big_cls + (size_t)i * TWB);
    hipLaunchKernelGGL(repack_big_k, dim3(2304), dim3(256), 0, stream,
                       box_w + (size_t)i * 256 * 2304, big_box + (size_t)i * TWB);
  }
  rp(logits_w, wpk_clsh, 80, 96, 0);
  rp(ctr_w, wpk_clsh, 1, 96, 80);
  rp(reg_w, wpk_regh, 4, 32, 0);

  const size_t OUT0 = (size_t)8 * TOT85;
  hipLaunchKernelGGL(locations_all_k, dim3(80), dim3(256), 0, stream, d_out + OUT0);

  dim3 gridT(97, 2, 8);   // towers: 32-col tiles x oc-half x batch
  dim3 gridH(182, 1, 8);  // heads: 16-col tiles x batch
  dim3 blkT(512), blkH(256);

  for (int t = 0; t < 2; ++t) {
    const __hip_bfloat16* bigT = (t == 0) ? big_cls : big_box;
    const float* bt = (t == 0) ? cls_b : box_b;
    const float* gt = (t == 0) ? cls_g : box_g;
    const float* bbt = (t == 0) ? cls_bb : box_bb;
    // stats slot(l,t,i) = l*4096 + (t*4+i)*512; kernels add l*4096
    auto slot = [&](int i) { return stats_all + (size_t)(t * 4 + i) * 512; };

    // conv 0: NCHW f32 input (all levels), no norm
    hipLaunchKernelGGL((conv_tower_k<false, true>), gridT, blkT, 0, stream, feats,
                       (const __hip_bfloat16*)nullptr, bigT, bt, (const float*)nullptr,
                       (const float*)nullptr, (const float*)nullptr, bufA, slot(0));
    __hip_bfloat16* cur = bufA;
    __hip_bfloat16* nxt = bufB;
    for (int i = 1; i < 4; ++i) {
      hipLaunchKernelGGL((conv_tower_k<true, false>), gridT, blkT, 0, stream, featsNull,
                         (const __hip_bfloat16*)cur, bigT + (size_t)i * TWB, bt + i * 256,
                         slot(i - 1), gt + (i - 1) * 256, bbt + (i - 1) * 256, nxt, slot(i));
      __hip_bfloat16* tmp = cur;
      cur = nxt;
      nxt = tmp;
    }
    if (t == 0) {
      hipLaunchKernelGGL((conv_head_k<3, 1>), gridH, blkH, 0, stream,
                         (const __hip_bfloat16*)cur, wpk_clsh, logits_b, ctr_b, slot(3),
                         gt + 3 * 256, bbt + 3 * 256, d_out, scales, 96);
    } else {
      hipLaunchKernelGGL((conv_head_k<1, 2>), gridH, blkH, 0, stream,
                         (const __hip_bfloat16*)cur, wpk_regh, reg_b, (const float*)nullptr,
                         slot(3), gt + 3 * 256, bbt + 3 * 256, d_out, scales, 32);
    }
  }
}

// Round 11
// 2393.418 us; speedup vs baseline: 1.0741x; 1.0741x over previous
//
#include <hip/hip_runtime.h>
#include <hip/hip_bf16.h>

#define TOT85 1722695ULL  // 85 * 20267

using short8 = __attribute__((ext_vector_type(8))) short;
using f32x4  = __attribute__((ext_vector_type(4))) float;

struct Feat5 { const float* p[5]; };
struct TowerPtrs {
  const __hip_bfloat16* wpk;
  const float* bias;
  const float* statsIn;
  const float* gamma;
  const float* beta;
  const __hip_bfloat16* src;
  __hip_bfloat16* dst;
  float* statsOut;
};
struct TowerArgs { TowerPtrs t0, t1; };

__device__ __forceinline__ float bfbits2f(short u) {
  return __uint_as_float(((unsigned int)(unsigned short)u) << 16);
}
__device__ __forceinline__ short f2bfbits(float f) {
  __hip_bfloat16 h = __float2bfloat16(f);
  return *reinterpret_cast<short*>(&h);
}

// level tables (compile-time; FEAT_SHAPES fixed). 16-col tiling, 182 tiles.
#define LVL_TABLES                                                              \
  constexpr int kH[5] = {100, 50, 25, 13, 7};                                   \
  constexpr int kW[5] = {152, 76, 38, 19, 10};                                  \
  constexpr int kNTx[5] = {10, 5, 3, 2, 1};                                     \
  constexpr int kCumT[5] = {0, 130, 165, 177, 181};                             \
  constexpr int kCumHW[5] = {0, 15200, 19000, 19950, 20197};                    \
  constexpr float kInv[5] = {1.f / 121600.f, 1.f / 30400.f, 1.f / 7600.f,       \
                             1.f / 1976.f, 1.f / 560.f};

// all 8 tower convs repacked in ONE dispatch: y = tower*4 + conv
// [O=256][256][3][3] f32 -> [tap*8+chunk][256 oc][32 ic] bf16
__global__ __launch_bounds__(256) void repack_tower_k(const float* __restrict__ cls_w,
                                                      const float* __restrict__ box_w,
                                                      __hip_bfloat16* __restrict__ dst_cls,
                                                      __hip_bfloat16* __restrict__ dst_box) {
  const size_t TW = (size_t)9 * 8 * 256 * 32;
  int y = blockIdx.y;
  const float* src = (y < 4) ? cls_w + (size_t)y * 256 * 2304
                             : box_w + (size_t)(y - 4) * 256 * 2304;
  __hip_bfloat16* dst = (y < 4) ? dst_cls + (size_t)y * TW
                                : dst_box + (size_t)(y - 4) * TW;
  int idx = blockIdx.x * 256 + threadIdx.x;  // exactly 256*2304
  int o = idx / 2304;
  int r = idx - o * 2304;
  int i = r / 9;       // ic 0..255
  int t = r - i * 9;   // tap 0..8
  dst[((size_t)(t * 8 + (i >> 5)) * 256 + o) * 32 + (i & 31)] =
      __float2bfloat16(src[idx]);
}

// head-layout repack: [O][256][3][3] f32 -> [tap*8+chunk][NOCP oc][32 ic] bf16
__global__ __launch_bounds__(256) void repack_k(const float* __restrict__ src,
                                                __hip_bfloat16* __restrict__ dst,
                                                int O, int NOCP, int ocoff) {
  int idx = blockIdx.x * 256 + threadIdx.x;
  if (idx >= O * 2304) return;
  int o = idx / 2304;
  int r = idx - o * 2304;
  int i = r / 9;
  int t = r - i * 9;
  dst[((size_t)(t * 8 + (i >> 5)) * NOCP + (o + ocoff)) * 32 + (i & 31)] =
      __float2bfloat16(src[idx]);
}

__global__ void locations_all_k(float* __restrict__ out) {
  LVL_TABLES
  constexpr int kStride[5] = {8, 16, 32, 64, 128};
  int i = blockIdx.x * 256 + threadIdx.x;
  if (i >= 20267) return;
  int lvl = (i >= 15200) + (i >= 19000) + (i >= 19950) + (i >= 20197);
  int local = i - kCumHW[lvl];
  int W = kW[lvl];
  float s = (float)kStride[lvl];
  int y = local / W, x = local - y * W;
  out[2 * i + 0] = x * s + 0.5f * s;
  out[2 * i + 1] = y * s + 0.5f * s;
}

// ---------------- tower kernel (r9-verified engine; blockIdx.y selects tower) --------
// Block: 256 thr = 4 waves (2M x 2N). Tile: 128 px (8 rows x 16 cols) x 256 ocs.
// grid.x = 182 tiles across all levels; grid.y = tower (cls/box); grid.z = batch.
// 4 chunks of 64 ic; s_in [180][72] (stride 72 shorts -> 2-way bank-free);
// 18 K-steps/chunk, weights global->VGPR double-buffered 1 step ahead; 8 barriers.
// 2-phase staging: loads issued to regs before barrier 1, convert+ds_write after.
template <bool NORM_IN, bool SRC_NCHW>
__global__ __launch_bounds__(256, 2) void conv_tower_k(Feat5 feats, TowerArgs args) {
  LVL_TABLES
  __shared__ __align__(16) short s_in[180 * 72];
  __shared__ float s_red[64];
  __shared__ float s_a[256], s_c[256];

  TowerPtrs P;
  if (blockIdx.y == 0) P = args.t0; else P = args.t1;

  const int tid = threadIdx.x;
  const int lane = tid & 63;
  const int wave = tid >> 6;
  const int wm = wave >> 1;  // 0..1
  const int wn = wave & 1;   // 0..1
  const int bx = blockIdx.x;
  const int lvl = (bx >= 130) + (bx >= 165) + (bx >= 177) + (bx >= 181);
  const int H = kH[lvl], W = kW[lvl], nTx = kNTx[lvl];
  const int tloc = bx - kCumT[lvl];
  const int ty = tloc / nTx, tx = tloc - ty * nTx;
  const int x0 = tx * 16, y0 = ty * 8;
  const int b = blockIdx.z;
  const int HW = H * W;
  const size_t lbase = (size_t)2048 * kCumHW[lvl];  // 8*256*cumHW elements
  const int l15 = lane & 15;
  const int kg = lane >> 4;       // 0..3
  const int q8x = (tid & 7) * 8;  // 8 ic-quads per 64-ic chunk

  if (tid < 64) s_red[tid] = 0.f;
  if (NORM_IN) {
    const float* statsIn = P.statsIn + (size_t)lvl * 4096;
    float inv_cnt = kInv[lvl];
    int g = tid >> 3;
    float s = statsIn[(b * 32 + g) * 2 + 0];
    float ss = statsIn[(b * 32 + g) * 2 + 1];
    float m = s * inv_cnt;
    float var = fmaf(-m, m, ss * inv_cnt);
    float rs = rsqrtf(var + 1e-5f);
    float avv = rs * P.gamma[tid];
    s_a[tid] = avv;
    s_c[tid] = fmaf(-m, avv, P.beta[tid]);
  }

  f32x4 acc[4][8];
#pragma unroll
  for (int m = 0; m < 4; ++m)
#pragma unroll
    for (int n = 0; n < 8; ++n) acc[m][n] = (f32x4){0.f, 0.f, 0.f, 0.f};

  // per-lane weight pointer: elem = ((tap*8+chunk32)*256 + wn*128 + n*16 + l15)*32 + kg*8
  const short* wlane = (const short*)P.wpk + ((wn * 128 + l15) * 32 + kg * 8);

  // pixel geometry for the NCHW staging role
  const int pixN = tid;
  int prowN = pixN / 18;
  int pcolN = pixN - prowN * 18;
  const int gyN = y0 + prowN - 1, gxN = x0 + pcolN - 1;
  const bool validN = (pixN < 180) && (gyN >= 0 && gyN < H && gxN >= 0 && gxN < W);

  for (int c = 0; c < 4; ++c) {
    const int ic0 = c * 64;

    // ---- phase A: issue global loads into regs (no LDS touch -> before barrier) ----
    short8 pv[6];
    float fv[32];
    if (SRC_NCHW) {
      const float* srcf = feats.p[lvl];
      if (validN) {
        const float* p = srcf + (((size_t)(b * 256 + ic0)) * H + gyN) * W + gxN;
#pragma unroll
        for (int j = 0; j < 32; ++j) fv[j] = p[(size_t)j * HW];
      }
    } else {
      const short* srcb = (const short*)P.src + lbase;
#pragma unroll
      for (int r = 0; r < 6; ++r) {
        int idx = r * 256 + tid;
        pv[r] = (short8)0;
        if (idx < 1440) {  // 180 px x 8 quads
          int px = idx >> 3;
          int prow = px / 18;
          int pcol = px - prow * 18;
          int gy = y0 + prow - 1, gx = x0 + pcol - 1;
          if (gy >= 0 && gy < H && gx >= 0 && gx < W)
            pv[r] = *(const short8*)(srcb +
                                     ((((size_t)b * H + gy) * W + gx) * 256 + ic0 + q8x));
        }
      }
    }

    __syncthreads();  // prev chunk's readers done; phase-A loads in flight during wait

    // ---- phase B: convert + LDS write ----
    if (SRC_NCHW) {
      const float* srcf = feats.p[lvl];
      if (pixN < 180) {
        short8 sv[4];
        if (validN) {
#pragma unroll
          for (int q = 0; q < 4; ++q)
#pragma unroll
            for (int j = 0; j < 8; ++j) sv[q][j] = f2bfbits(fv[q * 8 + j]);
        } else {
#pragma unroll
          for (int q = 0; q < 4; ++q) sv[q] = (short8)0;
        }
#pragma unroll
        for (int q = 0; q < 4; ++q) *(short8*)(s_in + pixN * 72 + q * 8) = sv[q];
        // second half (ic 32..63)
        if (validN) {
          const float* p = srcf + (((size_t)(b * 256 + ic0 + 32)) * H + gyN) * W + gxN;
#pragma unroll
          for (int j = 0; j < 32; ++j) fv[j] = p[(size_t)j * HW];
#pragma unroll
          for (int q = 0; q < 4; ++q)
#pragma unroll
            for (int j = 0; j < 8; ++j) sv[q][j] = f2bfbits(fv[q * 8 + j]);
        }
#pragma unroll
        for (int q = 0; q < 4; ++q) *(short8*)(s_in + pixN * 72 + 32 + q * 8) = sv[q];
      }
    } else {
      float av[8], cv[8];
#pragma unroll
      for (int j = 0; j < 8; ++j) {
        int c2 = ic0 + q8x + j;
        av[j] = s_a[c2];
        cv[j] = s_c[c2];
      }
#pragma unroll
      for (int r = 0; r < 6; ++r) {
        int idx = r * 256 + tid;
        if (idx < 1440) {
          int px = idx >> 3;
          int prow = px / 18;
          int pcol = px - prow * 18;
          int gy = y0 + prow - 1, gx = x0 + pcol - 1;
          short8 o8 = (short8)0;
          if (gy >= 0 && gy < H && gx >= 0 && gx < W) {
#pragma unroll
            for (int j = 0; j < 8; ++j)
              o8[j] = f2bfbits(fmaxf(fmaf(bfbits2f(pv[r][j]), av[j], cv[j]), 0.f));
          }
          *(short8*)(s_in + px * 72 + q8x) = o8;
        }
      }
    }
    __syncthreads();

    // ---- 18 K-steps (9 taps x 2 sub-chunks), weights double-buffered 1 step ahead ----
    const short* wcb = wlane + (size_t)c * 2 * 8192;  // chunk32 = c*2 + sub
    short8 bwA[8], bwB[8];
#pragma unroll
    for (int n = 0; n < 8; ++n) bwA[n] = *(const short8*)(wcb + n * 512);

    auto kbody = [&](int k, short8* curw, short8* nxtw) {
      if (k < 17) {  // prefetch next K-step's weights (L1/L2-resident)
        int kn = k + 1;
        const short* wt = wcb + ((size_t)((kn >> 1) * 8 + (kn & 1))) * 8192;
#pragma unroll
        for (int n = 0; n < 8; ++n) nxtw[n] = *(const short8*)(wt + n * 512);
      }
      const int tap = k >> 1, sub = k & 1;
      const int dy = tap / 3, dx = tap - dy * 3;
      short8 af[4];
#pragma unroll
      for (int m = 0; m < 4; ++m)
        af[m] = *(const short8*)(s_in + ((wm * 4 + m + dy) * 18 + (l15 + dx)) * 72 +
                                 sub * 32 + kg * 8);
#pragma unroll
      for (int m = 0; m < 4; ++m)
#pragma unroll
        for (int n = 0; n < 8; ++n)
          acc[m][n] = __builtin_amdgcn_mfma_f32_16x16x32_bf16(af[m], curw[n], acc[m][n], 0, 0, 0);
    };
#pragma unroll
    for (int k = 0; k < 18; k += 2) {
      kbody(k, bwA, bwB);
      kbody(k + 1, bwB, bwA);
    }
  }

  // epilogue: bias, NHWC bf16 store, GN stats
  short* dst = (short*)P.dst + lbase;
  const int masks[5] = {1, 2, 4, 16, 32};
#pragma unroll
  for (int n = 0; n < 8; ++n) {
    int oc_g = wn * 128 + n * 16 + l15;
    float bv = P.bias[oc_g];
    float lsum = 0.f, lssq = 0.f;
#pragma unroll
    for (int m = 0; m < 4; ++m) {
      int oy = y0 + wm * 4 + m;
#pragma unroll
      for (int r = 0; r < 4; ++r) {
        int ox = x0 + kg * 4 + r;
        bool valid = (oy < H) && (ox < W);
        float v = acc[m][n][r] + bv;
        if (valid) {
          dst[(((size_t)b * H + oy) * W + ox) * 256 + oc_g] = f2bfbits(v);
          lsum += v;
          lssq += v * v;
        }
      }
    }
#pragma unroll
    for (int s = 0; s < 5; ++s) {
      lsum += __shfl_xor(lsum, masks[s], 64);
      lssq += __shfl_xor(lssq, masks[s], 64);
    }
    if ((lane & 55) == 0) {  // lanes 0 and 8: two 8-oc GN sub-groups
      int g2 = ((wn * 8 + n) * 2 + ((lane >> 3) & 1)) * 2;
      atomicAdd(&s_red[g2 + 0], lsum);
      atomicAdd(&s_red[g2 + 1], lssq);
    }
  }
  __syncthreads();
  float* statsOut = P.statsOut + (size_t)lvl * 4096;
  if (tid < 64) atomicAdd(&statsOut[(size_t)b * 64 + tid], s_red[tid]);
}

// ---------------- head kernel (r9-proven 2Mx2N register path, level-batched) --------
// OUT_MODE: 1 = d_out fp32 (logits oc<80, ctr oc==80 -> ch84);
//           2 = d_out fp32 expf(scale*v) at ch 80+oc.
template <int NREP, int OUT_MODE>
__global__ __launch_bounds__(256, 3) void conv_head_k(
    const __hip_bfloat16* __restrict__ srcb_base, const __hip_bfloat16* __restrict__ wpk,
    const float* __restrict__ bias, const float* __restrict__ bias2,
    const float* __restrict__ statsInBase, const float* __restrict__ gamma,
    const float* __restrict__ beta, float* __restrict__ out,
    const float* __restrict__ scales, int NOCP) {
  LVL_TABLES
  __shared__ __align__(16) short s_in[180 * 40];
  __shared__ float s_a[256], s_c[256];

  const int tid = threadIdx.x;
  const int lane = tid & 63;
  const int wave = tid >> 6;
  const int wm = wave >> 1;
  const int wn = wave & 1;
  const int bx = blockIdx.x;
  const int lvl = (bx >= 130) + (bx >= 165) + (bx >= 177) + (bx >= 181);
  const int H = kH[lvl], W = kW[lvl], nTx = kNTx[lvl];
  const int tloc = bx - kCumT[lvl];
  const int ty = tloc / nTx, tx = tloc - ty * nTx;
  const int x0 = tx * 16, y0 = ty * 8;
  const int b = blockIdx.z;
  const int HW = H * W;
  const size_t lbase = (size_t)2048 * kCumHW[lvl];
  float* out_lvl = out + (size_t)85 * kCumHW[lvl];
  const int l15 = lane & 15;
  const int kg = lane >> 4;
  const int q8 = (tid & 3) * 8;

  {
    const float* statsIn = statsInBase + (size_t)lvl * 4096;
    float inv_cnt = kInv[lvl];
    int g = tid >> 3;
    float s = statsIn[(b * 32 + g) * 2 + 0];
    float ss = statsIn[(b * 32 + g) * 2 + 1];
    float m = s * inv_cnt;
    float var = fmaf(-m, m, ss * inv_cnt);
    float rs = rsqrtf(var + 1e-5f);
    float avv = rs * gamma[tid];
    s_a[tid] = avv;
    s_c[tid] = fmaf(-m, avv, beta[tid]);
  }

  f32x4 acc[4][NREP];
#pragma unroll
  for (int m = 0; m < 4; ++m)
#pragma unroll
    for (int n = 0; n < NREP; ++n) acc[m][n] = (f32x4){0.f, 0.f, 0.f, 0.f};

  const short* wlane = (const short*)wpk + ((wn * NREP * 16 + l15) * 32 + kg * 8);
  const size_t TAPSTR = (size_t)8 * NOCP * 32;

  for (int chunk = 0; chunk < 8; ++chunk) {
    const int ic0 = chunk * 32;
    __syncthreads();
    {
      const short* srcb = (const short*)srcb_base + lbase;
      float av[8], cv[8];
#pragma unroll
      for (int j = 0; j < 8; ++j) {
        int c2 = ic0 + q8 + j;
        av[j] = s_a[c2];
        cv[j] = s_c[c2];
      }
      for (int idx = tid; idx < 720; idx += 256) {
        int pix = idx >> 2;
        int prow = pix / 18;
        int pcol = pix - prow * 18;
        int gy = y0 + prow - 1, gx = x0 + pcol - 1;
        short8 o8 = (short8)0;
        if (gy >= 0 && gy < H && gx >= 0 && gx < W) {
          const short* sp = srcb + ((((size_t)b * H + gy) * W + gx) * 256 + ic0 + q8);
          short8 v8 = *(const short8*)sp;
#pragma unroll
          for (int j = 0; j < 8; ++j)
            o8[j] = f2bfbits(fmaxf(fmaf(bfbits2f(v8[j]), av[j], cv[j]), 0.f));
        }
        *(short8*)(s_in + pix * 40 + q8) = o8;
      }
    }
    __syncthreads();

    const short* wch = wlane + (size_t)chunk * NOCP * 32;
    short8 bwA[NREP], bwB[NREP];
#pragma unroll
    for (int n = 0; n < NREP; ++n) bwA[n] = *(const short8*)(wch + n * 512);

    auto tapbody = [&](int tap, short8* curw, short8* nxtw) {
      if (tap < 8) {
        const short* wt = wch + (size_t)(tap + 1) * TAPSTR;
#pragma unroll
        for (int n = 0; n < NREP; ++n) nxtw[n] = *(const short8*)(wt + n * 512);
      }
      const int dy = tap / 3, dx = tap - dy * 3;
      short8 af[4];
#pragma unroll
      for (int m = 0; m < 4; ++m)
        af[m] = *(const short8*)(s_in + ((wm * 4 + m + dy) * 18 + (l15 + dx)) * 40 + kg * 8);
#pragma unroll
      for (int m = 0; m < 4; ++m)
#pragma unroll
        for (int n = 0; n < NREP; ++n)
          acc[m][n] = __builtin_amdgcn_mfma_f32_16x16x32_bf16(af[m], curw[n], acc[m][n], 0, 0, 0);
    };
#pragma unroll
    for (int tap = 0; tap < 9; tap += 2) {
      tapbody(tap, bwA, bwB);
      if (tap + 1 < 9) tapbody(tap + 1, bwB, bwA);
    }
  }

#pragma unroll
  for (int n = 0; n < NREP; ++n) {
    int oc_l = wn * NREP * 16 + n * 16 + l15;
    int oc_valid = (OUT_MODE == 1) ? 81 : 4;
    float bv;
    if (OUT_MODE == 1)
      bv = (oc_l < 80) ? bias[oc_l] : ((oc_l == 80) ? bias2[0] : 0.f);
    else
      bv = (oc_l < oc_valid) ? bias[oc_l] : 0.f;
#pragma unroll
    for (int m = 0; m < 4; ++m) {
      int oy = y0 + wm * 4 + m;
#pragma unroll
      for (int r = 0; r < 4; ++r) {
        int ox = x0 + kg * 4 + r;
        bool valid = (oy < H) && (ox < W) && (oc_l < oc_valid);
        float v = acc[m][n][r] + bv;
        if (valid) {
          if (OUT_MODE == 1) {
            int och = (oc_l == 80) ? 84 : oc_l;
            out_lvl[(size_t)b * TOT85 + (size_t)och * HW + oy * W + ox] = v;
          } else {
            out_lvl[(size_t)b * TOT85 + (size_t)(80 + oc_l) * HW + oy * W + ox] =
                expf(scales[lvl] * v);
          }
        }
      }
    }
  }
}

extern "C" void kernel_launch(void* const* d_in, const int* in_sizes, int n_in,
                              void* d_out_v, int out_size, void* d_ws, size_t ws_size,
                              hipStream_t stream) {
  (void)in_sizes; (void)n_in; (void)out_size;

  Feat5 feats;
  for (int i = 0; i < 5; ++i) feats.p[i] = (const float*)d_in[i];
  const float* cls_w = (const float*)d_in[5];
  const float* cls_b = (const float*)d_in[6];
  const float* cls_g = (const float*)d_in[7];
  const float* cls_bb = (const float*)d_in[8];
  const float* box_w = (const float*)d_in[9];
  const float* box_b = (const float*)d_in[10];
  const float* box_g = (const float*)d_in[11];
  const float* box_bb = (const float*)d_in[12];
  const float* logits_w = (const float*)d_in[13];
  const float* logits_b = (const float*)d_in[14];
  const float* ctr_w = (const float*)d_in[15];
  const float* ctr_b = (const float*)d_in[16];
  const float* reg_w = (const float*)d_in[17];
  const float* reg_b = (const float*)d_in[18];
  const float* scales = (const float*)d_in[19];
  float* d_out = (float*)d_out_v;

  char* wsp = (char*)d_ws;
  size_t off = 0;
  auto carve = [&](size_t bytes) -> char* {
    char* p = wsp + off;
    off += (bytes + 255) & ~(size_t)255;
    return p;
  };
  const size_t ALLE = (size_t)8 * 20267 * 256;  // all levels concat, NHWC elems
  const size_t ALLEb = ALLE * 2;
  const size_t TW = (size_t)9 * 8 * 256 * 32;  // per tower conv (elems)
  const size_t FIXED = 8 * TW * 2 + (size_t)9 * 8 * 96 * 32 * 2 +
                       (size_t)9 * 8 * 32 * 32 * 2 + (size_t)40 * 512 * 4 + 64 * 256;
  const bool fused = (ws_size >= 4 * ALLEb + FIXED);

  __hip_bfloat16 *bufCA, *bufCB, *bufBA, *bufBB;
  bufCA = (__hip_bfloat16*)carve(ALLEb);
  bufCB = (__hip_bfloat16*)carve(ALLEb);
  if (fused) {
    bufBA = (__hip_bfloat16*)carve(ALLEb);
    bufBB = (__hip_bfloat16*)carve(ALLEb);
  } else {
    bufBA = bufCA;  // serial fallback shares the pair
    bufBB = bufCB;
  }
  __hip_bfloat16* wpk_cls = (__hip_bfloat16*)carve(4 * TW * 2);
  __hip_bfloat16* wpk_box = (__hip_bfloat16*)carve(4 * TW * 2);
  __hip_bfloat16* wpk_clsh = (__hip_bfloat16*)carve((size_t)9 * 8 * 96 * 32 * 2);
  __hip_bfloat16* wpk_regh = (__hip_bfloat16*)carve((size_t)9 * 8 * 32 * 32 * 2);
  float* stats_all = (float*)carve((size_t)40 * 512 * 4);

  hipMemsetAsync(stats_all, 0, (size_t)40 * 512 * 4, stream);

  hipLaunchKernelGGL(repack_tower_k, dim3(2304, 8), dim3(256), 0, stream, cls_w, box_w,
                     wpk_cls, wpk_box);
  auto rp = [&](const float* s, __hip_bfloat16* d, int O, int NOCP, int ocoff) {
    int total = O * 2304;
    hipLaunchKernelGGL(repack_k, dim3((total + 255) / 256), dim3(256), 0, stream, s, d, O, NOCP,
                       ocoff);
  };
  rp(logits_w, wpk_clsh, 80, 96, 0);
  rp(ctr_w, wpk_clsh, 1, 96, 80);
  rp(reg_w, wpk_regh, 4, 32, 0);

  const size_t OUT0 = (size_t)8 * TOT85;
  hipLaunchKernelGGL(locations_all_k, dim3(80), dim3(256), 0, stream, d_out + OUT0);

  // stats slot(l, tower, conv) = l*4096 + (tower*4+conv)*512; kernels add l*4096
  auto slot = [&](int t, int i) { return stats_all + (size_t)(t * 4 + i) * 512; };
  auto mkPtrs = [&](int t, int i, const __hip_bfloat16* src, __hip_bfloat16* dst) {
    TowerPtrs p;
    p.wpk = ((t == 0) ? wpk_cls : wpk_box) + (size_t)i * TW;
    p.bias = ((t == 0) ? cls_b : box_b) + i * 256;
    p.statsIn = (i == 0) ? nullptr : slot(t, i - 1);
    p.gamma = (i == 0) ? nullptr : ((t == 0) ? cls_g : box_g) + (i - 1) * 256;
    p.beta = (i == 0) ? nullptr : ((t == 0) ? cls_bb : box_bb) + (i - 1) * 256;
    p.src = src;
    p.dst = dst;
    p.statsOut = slot(t, i);
    return p;
  };

  dim3 blk(256);
  __hip_bfloat16 *curC = bufCA, *nxtC = bufCB, *curB = bufBA, *nxtB = bufBB;

  if (fused) {
    dim3 gridF(182, 2, 8);
    for (int i = 0; i < 4; ++i) {
      TowerArgs a;
      if (i == 0) {
        a.t0 = mkPtrs(0, 0, nullptr, curC);
        a.t1 = mkPtrs(1, 0, nullptr, curB);
        hipLaunchKernelGGL((conv_tower_k<false, true>), gridF, blk, 0, stream, feats, a);
      } else {
        a.t0 = mkPtrs(0, i, curC, nxtC);
        a.t1 = mkPtrs(1, i, curB, nxtB);
        hipLaunchKernelGGL((conv_tower_k<true, false>), gridF, blk, 0, stream, feats, a);
        __hip_bfloat16* tc = curC; curC = nxtC; nxtC = tc;
        __hip_bfloat16* tb = curB; curB = nxtB; nxtB = tb;
      }
    }
    hipLaunchKernelGGL((conv_head_k<3, 1>), dim3(182, 1, 8), blk, 0, stream,
                       (const __hip_bfloat16*)curC, wpk_clsh, logits_b, ctr_b, slot(0, 3),
                       cls_g + 3 * 256, cls_bb + 3 * 256, d_out, scales, 96);
    hipLaunchKernelGGL((conv_head_k<1, 2>), dim3(182, 1, 8), blk, 0, stream,
                       (const __hip_bfloat16*)curB, wpk_regh, reg_b, (const float*)nullptr,
                       slot(1, 3), box_g + 3 * 256, box_bb + 3 * 256, d_out, scales, 32);
  } else {
    // serial fallback (exact r9 structure): two chains sharing one buffer pair
    dim3 gridS(182, 1, 8);
    for (int t = 0; t < 2; ++t) {
      __hip_bfloat16* cur = bufCA;
      __hip_bfloat16* nxt = bufCB;
      {
        TowerArgs a;
        a.t0 = mkPtrs(t, 0, nullptr, cur);
        a.t1 = a.t0;
        hipLaunchKernelGGL((conv_tower_k<false, true>), gridS, blk, 0, stream, feats, a);
      }
      for (int i = 1; i < 4; ++i) {
        TowerArgs a;
        a.t0 = mkPtrs(t, i, cur, nxt);
        a.t1 = a.t0;
        hipLaunchKernelGGL((conv_tower_k<true, false>), gridS, blk, 0, stream, feats, a);
        __hip_bfloat16* tmp = cur; cur = nxt; nxt = tmp;
      }
      if (t == 0) {
        hipLaunchKernelGGL((conv_head_k<3, 1>), gridS, blk, 0, stream,
                           (const __hip_bfloat16*)cur, wpk_clsh, logits_b, ctr_b, slot(0, 3),
                           cls_g + 3 * 256, cls_bb + 3 * 256, d_out, scales, 96);
      } else {
        hipLaunchKernelGGL((conv_head_k<1, 2>), gridS, blk, 0, stream,
                           (const __hip_bfloat16*)cur, wpk_regh, reg_b, (const float*)nullptr,
                           slot(1, 3), box_g + 3 * 256, box_bb + 3 * 256, d_out, scales, 32);
      }
    }
  }
}